// Round 6
// baseline (387.806 us; speedup 1.0000x reference)
//
#include <hip/hip_runtime.h>
#include <hip/hip_bf16.h>
#include <math.h>
#include <stdint.h>
#include <string.h>

#define BB 8
#define SS 96
#define DD 768
#define RR 24
#define RSEQ 8
#define TAG 3
#define D3 2304   // 3*D
#define NC 72     // R*TAG

typedef __attribute__((ext_vector_type(8))) short bf16x8;
typedef __attribute__((ext_vector_type(4))) float f32x4;

// round-half-up f32 pair -> packed bf16x2: add,add,v_perm = 3 VALU.
static __device__ inline uint32_t pkrhu(float lo, float hi) {
  uint32_t a, b;
  memcpy(&a, &lo, 4);
  memcpy(&b, &hi, 4);
  return __builtin_amdgcn_perm(b + 0x8000u, a + 0x8000u, 0x07060302u);
}
// RNE f32 -> bf16 (cold paths)
static __device__ inline uint16_t bf16c(float v) {
  uint32_t u;
  memcpy(&u, &v, 4);
  u += 0x7FFFu + ((u >> 16) & 1u);
  return (uint16_t)(u >> 16);
}
static __device__ inline uint32_t pkrne(float lo, float hi) {
  uint32_t a, b;
  memcpy(&a, &lo, 4);
  memcpy(&b, &hi, 4);
  a += 0x7FFFu + ((a >> 16) & 1u);
  b += 0x7FFFu + ((b >> 16) & 1u);
  return (a >> 16) | (b & 0xFFFF0000u);
}
static __device__ inline float lo16f(uint32_t u) {
  const uint32_t v = u << 16;
  float f;
  memcpy(&f, &v, 4);
  return f;
}
static __device__ inline float hi16f(uint32_t u) {
  const uint32_t v = u & 0xFFFF0000u;
  float f;
  memcpy(&f, &v, 4);
  return f;
}

// ---------------------------------------------------------------------------
// Kernel P0: Wb[96][2304] bf16 = rel_W^T (rows 72..95 zero).
// ---------------------------------------------------------------------------
__global__ __launch_bounds__(256) void k_prepW(const float* __restrict__ relW,
                                               uint16_t* __restrict__ Wb) {
  const int e = blockIdx.x * 256 + threadIdx.x;  // 96*2304
  const int n = e / D3, k = e % D3;
  float v = (n < NC) ? relW[(size_t)k * NC + n] : 0.f;
  Wb[e] = bf16c(v);
}

// ---------------------------------------------------------------------------
// Kernel P1: T[2304][1536] bf16 = proj_W^T, 64x64 LDS-tiled transpose.
// ---------------------------------------------------------------------------
__global__ __launch_bounds__(256) void k_trans(const float* __restrict__ W,
                                               uint16_t* __restrict__ T) {
  __shared__ float tile[64][65];
  const int c0 = blockIdx.x * 64;
  const int r0 = blockIdx.y * 64;
  const int t = threadIdx.x;
  {
    const int tr = t >> 4;
    const int tc4 = (t & 15) * 4;
#pragma unroll
    for (int p = 0; p < 4; ++p) {
      const int r = tr + p * 16;
      const float4 v = *(const float4*)&W[(size_t)(r0 + r) * D3 + c0 + tc4];
      tile[r][tc4 + 0] = v.x;
      tile[r][tc4 + 1] = v.y;
      tile[r][tc4 + 2] = v.z;
      tile[r][tc4 + 3] = v.w;
    }
  }
  __syncthreads();
  {
    const int cc = t >> 4;
    const int rr4 = (t & 15) * 4;
#pragma unroll
    for (int p = 0; p < 4; ++p) {
      const int c = cc + p * 16;
      uint2 w;
      w.x = pkrne(tile[rr4 + 0][c], tile[rr4 + 1][c]);
      w.y = pkrne(tile[rr4 + 2][c], tile[rr4 + 3][c]);
      *(uint2*)&T[(size_t)(c0 + c) * (2 * DD) + r0 + rr4] = w;
    }
  }
}

// ---------------------------------------------------------------------------
// Kernel 1a: refine, serial part only. Per sample: G+S0 fused as one
// 8x104 product (cols 0..95 vs enc, 96..103 vs A), then the 24 collapsed
// attention steps. Writes P[8][96] f32 to ws. grid 8.
// ---------------------------------------------------------------------------
__global__ __launch_bounds__(256) void k_refA(const float* __restrict__ enc,
                                              const float* __restrict__ rel,
                                              float* __restrict__ Pst) {
  const int b = blockIdx.x;
  const int t = threadIdx.x;
  __shared__ float As[RSEQ][DD + 4];
  __shared__ float S0[RSEQ][SS];
  __shared__ float G[RSEQ][RSEQ];
  __shared__ float P[RSEQ][SS];
  __shared__ float sc[RSEQ][SS];
  const float scale = 0.036084391824351613f;  // 1/sqrt(768)

  const float* Ag = rel + (size_t)b * RSEQ * DD;
  for (int e = t; e < RSEQ * DD; e += 256) As[e / DD][e % DD] = Ag[e];
  for (int e = t; e < RSEQ * SS; e += 256) ((float*)P)[e] = 0.f;
  __syncthreads();

  // fused: M[r][s] for s in [0,104): s<96 -> S0 (A@enc^T), s>=96 -> G (A@A^T)
  const float* Eb = enc + (size_t)b * SS * DD;
  for (int e = t; e < RSEQ * (SS + RSEQ); e += 256) {
    const int r = e & 7, s = e >> 3;
    const float* row = (s < SS) ? (Eb + (size_t)s * DD) : &As[s - SS][0];
    float a0 = 0.f, a1 = 0.f, a2 = 0.f, a3 = 0.f;
    for (int d = 0; d < DD; d += 4) {
      const float4 rv = *(const float4*)&row[d];
      a0 += As[r][d + 0] * rv.x;
      a1 += As[r][d + 1] * rv.y;
      a2 += As[r][d + 2] * rv.z;
      a3 += As[r][d + 3] * rv.w;
    }
    const float acc = a0 + a1 + a2 + a3;
    if (s < SS) S0[r][s] = acc;
    else G[r][s - SS] = acc;
  }
  __syncthreads();

  const int wave = t >> 6, lane = t & 63;
  for (int step = 0; step < RR; ++step) {
    for (int e = t; e < RSEQ * SS; e += 256) {
      const int r = e / SS, s = e % SS;
      float acc = S0[r][s];
#pragma unroll
      for (int r2 = 0; r2 < RSEQ; ++r2) acc += G[r][r2] * P[r2][s];
      sc[r][s] = acc * scale;
    }
    __syncthreads();
#pragma unroll
    for (int rr = 0; rr < 2; ++rr) {
      const int r = wave * 2 + rr;
      const float m1 = sc[r][lane];
      const float m2 = (lane < 32) ? sc[r][lane + 64] : -1e30f;
      float mx = fmaxf(m1, m2);
#pragma unroll
      for (int o = 32; o > 0; o >>= 1) mx = fmaxf(mx, __shfl_xor(mx, o, 64));
      const float e1 = __expf(m1 - mx);
      const float e2 = (lane < 32) ? __expf(m2 - mx) : 0.f;
      float sm = e1 + e2;
#pragma unroll
      for (int o = 32; o > 0; o >>= 1) sm += __shfl_xor(sm, o, 64);
      const float inv = 1.f / sm;
      P[r][lane] += e1 * inv;
      if (lane < 32) P[r][lane + 64] += e2 * inv;
    }
    __syncthreads();
  }

  for (int e = t; e < RSEQ * SS; e += 256) Pst[(size_t)b * RSEQ * SS + e] = ((float*)P)[e];
}

// ---------------------------------------------------------------------------
// Kernel 1b: refine epilogue (parallel): enc' bf16 = enc + P^T @ A.
// grid 48 = 8 b x 6 chunks of 16 s-rows.
// ---------------------------------------------------------------------------
__global__ __launch_bounds__(256) void k_refB(const float* __restrict__ enc,
                                              const float* __restrict__ rel,
                                              const float* __restrict__ Pst,
                                              uint16_t* __restrict__ encRb) {
  const int blk = blockIdx.x;
  const int b = blk / 6;
  const int s0 = (blk % 6) * 16;
  const int t = threadIdx.x;
  __shared__ float As[RSEQ][DD + 4];
  __shared__ float Pl[RSEQ][16];

  const float* Ag = rel + (size_t)b * RSEQ * DD;
  for (int e = t; e < RSEQ * DD / 4; e += 256) {
    const int r = (e * 4) / DD, d = (e * 4) % DD;
    *(float4*)&As[r][d] = *(const float4*)&Ag[e * 4];
  }
  if (t < RSEQ * 16) {
    const int r = t >> 4, sl = t & 15;
    Pl[r][sl] = Pst[(size_t)b * RSEQ * SS + r * SS + s0 + sl];
  }
  __syncthreads();

  const float* Eb = enc + ((size_t)b * SS + s0) * DD;
  uint16_t* Ob = encRb + ((size_t)b * SS + s0) * DD;
  for (int e = t; e < 16 * DD / 4; e += 256) {
    const int sl = (e * 4) / DD, d = (e * 4) % DD;
    float4 v = ((const float4*)Eb)[e];
#pragma unroll
    for (int r = 0; r < RSEQ; ++r) {
      const float p = Pl[r][sl];
      v.x += p * As[r][d + 0];
      v.y += p * As[r][d + 1];
      v.z += p * As[r][d + 2];
      v.w += p * As[r][d + 3];
    }
    uint2 w;
    w.x = pkrhu(v.x, v.y);
    w.y = pkrhu(v.z, v.w);
    *(uint2*)&Ob[e * 4] = w;
  }
}

// ---------------------------------------------------------------------------
// Kernel 2: projection GEMM, bf16 MFMA, LDS-staged (unchanged from R5).
// ---------------------------------------------------------------------------
__global__ __launch_bounds__(256, 4) void k_proj(const uint16_t* __restrict__ Ab,
                                                 const uint16_t* __restrict__ Bt,
                                                 const float* __restrict__ pb,
                                                 float* __restrict__ Hh,
                                                 uint16_t* __restrict__ Htb) {
  const int m0 = blockIdx.x * 64;
  const int gn0 = blockIdx.y * 64;
  const bool isH = gn0 < D3;               // uniform per block
  const int n0 = isH ? gn0 : gn0 - D3;
  const int halfk = isH ? 0 : DD;
  const int t = threadIdx.x, w = t >> 6, lane = t & 63;
  const int wm = w >> 1, wn = w & 1;
  const int lm = lane & 15, q = lane >> 4;

  __shared__ uint16_t As[64][80];
  __shared__ uint16_t Bs[64][80];

  const int srow = t >> 3;
  const int sq8 = (t & 7) * 8;

  f32x4 acc[2][2];
#pragma unroll
  for (int a = 0; a < 2; ++a)
#pragma unroll
    for (int c = 0; c < 2; ++c) acc[a][c] = (f32x4){0.f, 0.f, 0.f, 0.f};

  const uint16_t* aSrc = Ab + (size_t)(m0 + srow) * DD + sq8;
  const uint16_t* bSrc = Bt + (size_t)(n0 + srow) * (2 * DD) + halfk + sq8;

  for (int k0 = 0; k0 < DD; k0 += 64) {
    const uint4 a0 = *(const uint4*)(aSrc + k0);
    const uint4 a1 = *(const uint4*)(aSrc + 32 * DD + k0);
    const uint4 b0 = *(const uint4*)(bSrc + k0);
    const uint4 b1 = *(const uint4*)(bSrc + 32 * (2 * DD) + k0);
    __syncthreads();
    *(uint4*)&As[srow][sq8] = a0;
    *(uint4*)&As[srow + 32][sq8] = a1;
    *(uint4*)&Bs[srow][sq8] = b0;
    *(uint4*)&Bs[srow + 32][sq8] = b1;
    __syncthreads();
#pragma unroll
    for (int kk = 0; kk < 2; ++kk) {
      bf16x8 af[2], bf[2];
#pragma unroll
      for (int mt = 0; mt < 2; ++mt)
        af[mt] = *(const bf16x8*)&As[wm * 32 + mt * 16 + lm][kk * 32 + q * 8];
#pragma unroll
      for (int nt = 0; nt < 2; ++nt)
        bf[nt] = *(const bf16x8*)&Bs[wn * 32 + nt * 16 + lm][kk * 32 + q * 8];
#pragma unroll
      for (int nt = 0; nt < 2; ++nt)
#pragma unroll
        for (int mt = 0; mt < 2; ++mt)
          acc[mt][nt] = __builtin_amdgcn_mfma_f32_16x16x32_bf16(af[mt], bf[nt], acc[mt][nt], 0, 0, 0);
    }
  }

#pragma unroll
  for (int nt = 0; nt < 2; ++nt) {
    const int ncol = n0 + wn * 32 + nt * 16 + lm;
    const int mrow = m0 + wm * 32 + q * 4;
    if (isH) {
      const float bias = pb[ncol];
#pragma unroll
      for (int mt = 0; mt < 2; ++mt)
#pragma unroll
        for (int r = 0; r < 4; ++r)
          Hh[(size_t)(mrow + mt * 16 + r) * D3 + ncol] = acc[mt][nt][r] + bias;
    } else {
#pragma unroll
      for (int mt = 0; mt < 2; ++mt)
#pragma unroll
        for (int r = 0; r < 4; ++r)
          Htb[(size_t)(mrow + mt * 16 + r) * D3 + ncol] = bf16c(acc[mt][nt][r]);
    }
  }
}

// ---------------------------------------------------------------------------
// Kernel 3: pairwise GEMM v4. Grid 768 = (b,i); 6 waves; wave w = j-tile
// [16w,16w+16) x all 5 n-tiles. R4's occupancy (3 blocks/CU, up to 18
// waves/CU) + R5's register budget (launch_bounds(384,3)) + explicit
// 1-chunk-ahead prefetch of BOTH the VMEM (Ht,Wb) and the LDS (Hrow) reads,
// so no latency sits on the critical path. One barrier total.
// ---------------------------------------------------------------------------
__global__ __launch_bounds__(384, 3) void k_pairs(const float* __restrict__ Hh,
                                                  const uint16_t* __restrict__ Htb,
                                                  const uint16_t* __restrict__ Wb,
                                                  const float* __restrict__ relb,
                                                  float* __restrict__ out) {
  const int bi = blockIdx.x;
  const int b = bi / SS, i = bi % SS;
  const int t = threadIdx.x;
  const int w = t >> 6, lane = t & 63;
  const int lm = lane & 15, q = lane >> 4;

  __shared__ float Hrow[D3];  // 9.2 KB

  const float* hh = Hh + (size_t)bi * D3;
  for (int e = t; e < D3 / 4; e += 384) ((float4*)Hrow)[e] = ((const float4*)hh)[e];
  __syncthreads();  // the only barrier

  const uint16_t* htrow = Htb + ((size_t)b * SS + w * 16 + lm) * D3 + q * 8;
  const uint16_t* wbp = Wb + (size_t)lm * D3 + q * 8;

  f32x4 acc[5];
#pragma unroll
  for (int nt = 0; nt < 5; ++nt) acc[nt] = (f32x4){0.f, 0.f, 0.f, 0.f};

  // prime chunk-0 operands (VMEM + LDS)
  uint4 htc = *(const uint4*)htrow;
  bf16x8 bc[5];
#pragma unroll
  for (int nt = 0; nt < 5; ++nt) bc[nt] = *(const bf16x8*)(wbp + (size_t)nt * 16 * D3);
  float4 hr0c = *(const float4*)&Hrow[q * 8];
  float4 hr1c = *(const float4*)&Hrow[q * 8 + 4];

  for (int k0 = 0; k0 < D3; k0 += 32) {
    const int kn = (k0 + 32 < D3) ? k0 + 32 : 0;  // last iter: harmless reload
    // prefetch next chunk: global...
    const uint4 htn = *(const uint4*)(htrow + kn);
    bf16x8 bn[5];
#pragma unroll
    for (int nt = 0; nt < 5; ++nt) bn[nt] = *(const bf16x8*)(wbp + (size_t)nt * 16 * D3 + kn);
    // ...and LDS (broadcast ds_read_b128 x2)
    const float4 hr0n = *(const float4*)&Hrow[kn + q * 8];
    const float4 hr1n = *(const float4*)&Hrow[kn + q * 8 + 4];

    // A-frag from CURRENT (all operands prefetched a full chunk ago)
    union { bf16x8 v; uint32_t u[4]; } pk;
    pk.u[0] = pkrhu(fmaxf(lo16f(htc.x) + hr0c.x, 0.f), fmaxf(hi16f(htc.x) + hr0c.y, 0.f));
    pk.u[1] = pkrhu(fmaxf(lo16f(htc.y) + hr0c.z, 0.f), fmaxf(hi16f(htc.y) + hr0c.w, 0.f));
    pk.u[2] = pkrhu(fmaxf(lo16f(htc.z) + hr1c.x, 0.f), fmaxf(hi16f(htc.z) + hr1c.y, 0.f));
    pk.u[3] = pkrhu(fmaxf(lo16f(htc.w) + hr1c.z, 0.f), fmaxf(hi16f(htc.w) + hr1c.w, 0.f));

#pragma unroll
    for (int nt = 0; nt < 5; ++nt)
      acc[nt] = __builtin_amdgcn_mfma_f32_16x16x32_bf16(pk.v, bc[nt], acc[nt], 0, 0, 0);

    htc = htn;
    hr0c = hr0n;
    hr1c = hr1n;
#pragma unroll
    for (int nt = 0; nt < 5; ++nt) bc[nt] = bn[nt];
  }

  // epilogue: C layout col=lm (c), row=q*4+r (j within tile)
#pragma unroll
  for (int nt = 0; nt < 5; ++nt) {
    const int c = nt * 16 + lm;
    if (c < NC) {
      const float rb = relb[c];
      const int r = c / 3, tg = c % 3;
      float* base = out + ((((size_t)b * TAG + tg) * RR + r) * SS + i) * SS + w * 16 + q * 4;
      float4 o;
      o.x = acc[nt][0] + rb;
      o.y = acc[nt][1] + rb;
      o.z = acc[nt][2] + rb;
      o.w = acc[nt][3] + rb;
      *(float4*)base = o;
    }
  }
}

// ---------------------------------------------------------------------------
extern "C" void kernel_launch(void* const* d_in, const int* in_sizes, int n_in,
                              void* d_out, int out_size, void* d_ws, size_t ws_size,
                              hipStream_t stream) {
  const float* enc   = (const float*)d_in[0];  // [8,96,768]
  const float* rel   = (const float*)d_in[1];  // [24,8,768]
  const float* projW = (const float*)d_in[2];  // [1536,2304]
  const float* projb = (const float*)d_in[3];  // [2304]
  const float* relW  = (const float*)d_in[4];  // [2304,72]
  const float* relb  = (const float*)d_in[5];  // [72]
  float* out = (float*)d_out;                  // [8,3,24,96,96]

  float* Hh = (float*)d_ws;                               // 768*2304 f32
  uint16_t* Htb = (uint16_t*)(Hh + (size_t)DD * D3);      // 768*2304 bf16
  uint16_t* Wb = Htb + (size_t)DD * D3;                   // 96*2304 bf16
  uint16_t* Tp = Wb + (size_t)96 * D3;                    // 2304*1536 bf16
  uint16_t* Ab = Tp + (size_t)D3 * 2 * DD;                // 768*768 bf16
  float* Pst = (float*)(Ab + (size_t)DD * DD);            // 8*8*96 f32

  k_prepW<<<(96 * D3) / 256, 256, 0, stream>>>(relW, Wb);
  k_trans<<<dim3(36, 24), 256, 0, stream>>>(projW, Tp);
  k_refA<<<BB, 256, 0, stream>>>(enc, rel, Pst);
  k_refB<<<48, 256, 0, stream>>>(enc, rel, Pst, Ab);
  k_proj<<<dim3(12, 72), 256, 0, stream>>>(Ab, Tp, projb, Hh, Htb);
  k_pairs<<<BB * SS, 384, 0, stream>>>(Hh, Htb, Wb, relb, out);
}

// Round 8
// 317.805 us; speedup vs baseline: 1.2203x; 1.2203x over previous
//
#include <hip/hip_runtime.h>
#include <hip/hip_bf16.h>
#include <math.h>
#include <stdint.h>
#include <string.h>

#define BB 8
#define SS 96
#define DD 768
#define RR 24
#define RSEQ 8
#define TAG 3
#define D3 2304   // 3*D
#define NC 72     // R*TAG

typedef __attribute__((ext_vector_type(8))) short bf16x8;
typedef __attribute__((ext_vector_type(4))) float f32x4;

// round-half-up f32 pair -> packed bf16x2: add,add,v_perm = 3 VALU.
static __device__ inline uint32_t pkrhu(float lo, float hi) {
  uint32_t a, b;
  memcpy(&a, &lo, 4);
  memcpy(&b, &hi, 4);
  return __builtin_amdgcn_perm(b + 0x8000u, a + 0x8000u, 0x07060302u);
}
// RNE f32 -> bf16 (cold paths)
static __device__ inline uint16_t bf16c(float v) {
  uint32_t u;
  memcpy(&u, &v, 4);
  u += 0x7FFFu + ((u >> 16) & 1u);
  return (uint16_t)(u >> 16);
}
static __device__ inline uint32_t pkrne(float lo, float hi) {
  uint32_t a, b;
  memcpy(&a, &lo, 4);
  memcpy(&b, &hi, 4);
  a += 0x7FFFu + ((a >> 16) & 1u);
  b += 0x7FFFu + ((b >> 16) & 1u);
  return (a >> 16) | (b & 0xFFFF0000u);
}
static __device__ inline float lo16f(uint32_t u) {
  const uint32_t v = u << 16;
  float f;
  memcpy(&f, &v, 4);
  return f;
}
static __device__ inline float hi16f(uint32_t u) {
  const uint32_t v = u & 0xFFFF0000u;
  float f;
  memcpy(&f, &v, 4);
  return f;
}

// ---------------------------------------------------------------------------
// Kernel P0: Wb[96][2304] bf16 = rel_W^T (rows 72..95 zero).
// ---------------------------------------------------------------------------
__global__ __launch_bounds__(256) void k_prepW(const float* __restrict__ relW,
                                               uint16_t* __restrict__ Wb) {
  const int e = blockIdx.x * 256 + threadIdx.x;  // 96*2304
  const int n = e / D3, k = e % D3;
  float v = (n < NC) ? relW[(size_t)k * NC + n] : 0.f;
  Wb[e] = bf16c(v);
}

// ---------------------------------------------------------------------------
// Kernel P1: T[2304][1536] bf16 = proj_W^T, 64x64 LDS-tiled transpose.
// ---------------------------------------------------------------------------
__global__ __launch_bounds__(256) void k_trans(const float* __restrict__ W,
                                               uint16_t* __restrict__ T) {
  __shared__ float tile[64][65];
  const int c0 = blockIdx.x * 64;
  const int r0 = blockIdx.y * 64;
  const int t = threadIdx.x;
  {
    const int tr = t >> 4;
    const int tc4 = (t & 15) * 4;
#pragma unroll
    for (int p = 0; p < 4; ++p) {
      const int r = tr + p * 16;
      const float4 v = *(const float4*)&W[(size_t)(r0 + r) * D3 + c0 + tc4];
      tile[r][tc4 + 0] = v.x;
      tile[r][tc4 + 1] = v.y;
      tile[r][tc4 + 2] = v.z;
      tile[r][tc4 + 3] = v.w;
    }
  }
  __syncthreads();
  {
    const int cc = t >> 4;
    const int rr4 = (t & 15) * 4;
#pragma unroll
    for (int p = 0; p < 4; ++p) {
      const int c = cc + p * 16;
      uint2 w;
      w.x = pkrne(tile[rr4 + 0][c], tile[rr4 + 1][c]);
      w.y = pkrne(tile[rr4 + 2][c], tile[rr4 + 3][c]);
      *(uint2*)&T[(size_t)(c0 + c) * (2 * DD) + r0 + rr4] = w;
    }
  }
}

// ---------------------------------------------------------------------------
// Kernel 1a: refine, serial part. G+S0 fused 8x104 product, then 24
// collapsed attention steps. Writes P[8][96]. grid 8.
// ---------------------------------------------------------------------------
__global__ __launch_bounds__(256) void k_refA(const float* __restrict__ enc,
                                              const float* __restrict__ rel,
                                              float* __restrict__ Pst) {
  const int b = blockIdx.x;
  const int t = threadIdx.x;
  __shared__ float As[RSEQ][DD + 4];
  __shared__ float S0[RSEQ][SS];
  __shared__ float G[RSEQ][RSEQ];
  __shared__ float P[RSEQ][SS];
  __shared__ float sc[RSEQ][SS];
  const float scale = 0.036084391824351613f;  // 1/sqrt(768)

  const float* Ag = rel + (size_t)b * RSEQ * DD;
  for (int e = t; e < RSEQ * DD; e += 256) As[e / DD][e % DD] = Ag[e];
  for (int e = t; e < RSEQ * SS; e += 256) ((float*)P)[e] = 0.f;
  __syncthreads();

  const float* Eb = enc + (size_t)b * SS * DD;
  for (int e = t; e < RSEQ * (SS + RSEQ); e += 256) {
    const int r = e & 7, s = e >> 3;
    const float* row = (s < SS) ? (Eb + (size_t)s * DD) : &As[s - SS][0];
    float a0 = 0.f, a1 = 0.f, a2 = 0.f, a3 = 0.f;
    for (int d = 0; d < DD; d += 4) {
      const float4 rv = *(const float4*)&row[d];
      a0 += As[r][d + 0] * rv.x;
      a1 += As[r][d + 1] * rv.y;
      a2 += As[r][d + 2] * rv.z;
      a3 += As[r][d + 3] * rv.w;
    }
    const float acc = a0 + a1 + a2 + a3;
    if (s < SS) S0[r][s] = acc;
    else G[r][s - SS] = acc;
  }
  __syncthreads();

  const int wave = t >> 6, lane = t & 63;
  for (int step = 0; step < RR; ++step) {
    for (int e = t; e < RSEQ * SS; e += 256) {
      const int r = e / SS, s = e % SS;
      float acc = S0[r][s];
#pragma unroll
      for (int r2 = 0; r2 < RSEQ; ++r2) acc += G[r][r2] * P[r2][s];
      sc[r][s] = acc * scale;
    }
    __syncthreads();
#pragma unroll
    for (int rr = 0; rr < 2; ++rr) {
      const int r = wave * 2 + rr;
      const float m1 = sc[r][lane];
      const float m2 = (lane < 32) ? sc[r][lane + 64] : -1e30f;
      float mx = fmaxf(m1, m2);
#pragma unroll
      for (int o = 32; o > 0; o >>= 1) mx = fmaxf(mx, __shfl_xor(mx, o, 64));
      const float e1 = __expf(m1 - mx);
      const float e2 = (lane < 32) ? __expf(m2 - mx) : 0.f;
      float sm = e1 + e2;
#pragma unroll
      for (int o = 32; o > 0; o >>= 1) sm += __shfl_xor(sm, o, 64);
      const float inv = 1.f / sm;
      P[r][lane] += e1 * inv;
      if (lane < 32) P[r][lane + 64] += e2 * inv;
    }
    __syncthreads();
  }

  for (int e = t; e < RSEQ * SS; e += 256) Pst[(size_t)b * RSEQ * SS + e] = ((float*)P)[e];
}

// ---------------------------------------------------------------------------
// Kernel 1b: refine epilogue (parallel): enc' bf16 = enc + P^T @ A. grid 48.
// ---------------------------------------------------------------------------
__global__ __launch_bounds__(256) void k_refB(const float* __restrict__ enc,
                                              const float* __restrict__ rel,
                                              const float* __restrict__ Pst,
                                              uint16_t* __restrict__ encRb) {
  const int blk = blockIdx.x;
  const int b = blk / 6;
  const int s0 = (blk % 6) * 16;
  const int t = threadIdx.x;
  __shared__ float As[RSEQ][DD + 4];
  __shared__ float Pl[RSEQ][16];

  const float* Ag = rel + (size_t)b * RSEQ * DD;
  for (int e = t; e < RSEQ * DD / 4; e += 256) {
    const int r = (e * 4) / DD, d = (e * 4) % DD;
    *(float4*)&As[r][d] = *(const float4*)&Ag[e * 4];
  }
  if (t < RSEQ * 16) {
    const int r = t >> 4, sl = t & 15;
    Pl[r][sl] = Pst[(size_t)b * RSEQ * SS + r * SS + s0 + sl];
  }
  __syncthreads();

  const float* Eb = enc + ((size_t)b * SS + s0) * DD;
  uint16_t* Ob = encRb + ((size_t)b * SS + s0) * DD;
  for (int e = t; e < 16 * DD / 4; e += 256) {
    const int sl = (e * 4) / DD, d = (e * 4) % DD;
    float4 v = ((const float4*)Eb)[e];
#pragma unroll
    for (int r = 0; r < RSEQ; ++r) {
      const float p = Pl[r][sl];
      v.x += p * As[r][d + 0];
      v.y += p * As[r][d + 1];
      v.z += p * As[r][d + 2];
      v.w += p * As[r][d + 3];
    }
    uint2 w;
    w.x = pkrhu(v.x, v.y);
    w.y = pkrhu(v.z, v.w);
    *(uint2*)&Ob[e * 4] = w;
  }
}

// ---------------------------------------------------------------------------
// Kernel 2: projection GEMM, bf16 MFMA, LDS-staged (unchanged).
// ---------------------------------------------------------------------------
__global__ __launch_bounds__(256, 4) void k_proj(const uint16_t* __restrict__ Ab,
                                                 const uint16_t* __restrict__ Bt,
                                                 const float* __restrict__ pb,
                                                 float* __restrict__ Hh,
                                                 uint16_t* __restrict__ Htb) {
  const int m0 = blockIdx.x * 64;
  const int gn0 = blockIdx.y * 64;
  const bool isH = gn0 < D3;               // uniform per block
  const int n0 = isH ? gn0 : gn0 - D3;
  const int halfk = isH ? 0 : DD;
  const int t = threadIdx.x, w = t >> 6, lane = t & 63;
  const int wm = w >> 1, wn = w & 1;
  const int lm = lane & 15, q = lane >> 4;

  __shared__ uint16_t As[64][80];
  __shared__ uint16_t Bs[64][80];

  const int srow = t >> 3;
  const int sq8 = (t & 7) * 8;

  f32x4 acc[2][2];
#pragma unroll
  for (int a = 0; a < 2; ++a)
#pragma unroll
    for (int c = 0; c < 2; ++c) acc[a][c] = (f32x4){0.f, 0.f, 0.f, 0.f};

  const uint16_t* aSrc = Ab + (size_t)(m0 + srow) * DD + sq8;
  const uint16_t* bSrc = Bt + (size_t)(n0 + srow) * (2 * DD) + halfk + sq8;

  for (int k0 = 0; k0 < DD; k0 += 64) {
    const uint4 a0 = *(const uint4*)(aSrc + k0);
    const uint4 a1 = *(const uint4*)(aSrc + 32 * DD + k0);
    const uint4 b0 = *(const uint4*)(bSrc + k0);
    const uint4 b1 = *(const uint4*)(bSrc + 32 * (2 * DD) + k0);
    __syncthreads();
    *(uint4*)&As[srow][sq8] = a0;
    *(uint4*)&As[srow + 32][sq8] = a1;
    *(uint4*)&Bs[srow][sq8] = b0;
    *(uint4*)&Bs[srow + 32][sq8] = b1;
    __syncthreads();
#pragma unroll
    for (int kk = 0; kk < 2; ++kk) {
      bf16x8 af[2], bf[2];
#pragma unroll
      for (int mt = 0; mt < 2; ++mt)
        af[mt] = *(const bf16x8*)&As[wm * 32 + mt * 16 + lm][kk * 32 + q * 8];
#pragma unroll
      for (int nt = 0; nt < 2; ++nt)
        bf[nt] = *(const bf16x8*)&Bs[wn * 32 + nt * 16 + lm][kk * 32 + q * 8];
#pragma unroll
      for (int nt = 0; nt < 2; ++nt)
#pragma unroll
        for (int mt = 0; mt < 2; ++mt)
          acc[mt][nt] = __builtin_amdgcn_mfma_f32_16x16x32_bf16(af[mt], bf[nt], acc[mt][nt], 0, 0, 0);
    }
  }

#pragma unroll
  for (int nt = 0; nt < 2; ++nt) {
    const int ncol = n0 + wn * 32 + nt * 16 + lm;
    const int mrow = m0 + wm * 32 + q * 4;
    if (isH) {
      const float bias = pb[ncol];
#pragma unroll
      for (int mt = 0; mt < 2; ++mt)
#pragma unroll
        for (int r = 0; r < 4; ++r)
          Hh[(size_t)(mrow + mt * 16 + r) * D3 + ncol] = acc[mt][nt][r] + bias;
    } else {
#pragma unroll
      for (int mt = 0; mt < 2; ++mt)
#pragma unroll
        for (int r = 0; r < 4; ++r)
          Htb[(size_t)(mrow + mt * 16 + r) * D3 + ncol] = bf16c(acc[mt][nt][r]);
    }
  }
}

// ---------------------------------------------------------------------------
// Kernel 3: pairwise GEMM v5 (R7 design, grid bug fixed: 8*48 = 384).
// Block = (b, 2 i's), 6 waves, wave = one 16-j tile x 2 i x 5 n-tiles
// (acc[2][5]=40 VGPR -- keeps backend out of its 32-VGPR serialized
// schedule, per R4/R5/R6 evidence). Grid 384 (~1.5 blocks/CU, ~9 waves/CU).
// 1-deep prefetch of Ht, Wb, and the LDS hr reads. One barrier total.
// ---------------------------------------------------------------------------
__global__ __launch_bounds__(384, 2) void k_pairs(const float* __restrict__ Hh,
                                                  const uint16_t* __restrict__ Htb,
                                                  const uint16_t* __restrict__ Wb,
                                                  const float* __restrict__ relb,
                                                  float* __restrict__ out) {
  const int blk = blockIdx.x;
  const int b = blk / 48;             // 0..7
  const int i0 = (blk % 48) * 2;      // 2 consecutive i
  const int t = threadIdx.x;
  const int w = t >> 6, lane = t & 63;
  const int lm = lane & 15, q = lane >> 4;

  __shared__ float Hrow[2 * D3];  // 18.4 KB

  const float* hh = Hh + ((size_t)b * SS + i0) * D3;
  for (int e = t; e < 2 * D3 / 4; e += 384) ((float4*)Hrow)[e] = ((const float4*)hh)[e];
  __syncthreads();  // the only barrier

  const uint16_t* htrow = Htb + ((size_t)b * SS + w * 16 + lm) * D3 + q * 8;
  const uint16_t* wbp = Wb + (size_t)lm * D3 + q * 8;

  f32x4 acc[2][5];
#pragma unroll
  for (int il = 0; il < 2; ++il)
#pragma unroll
    for (int nt = 0; nt < 5; ++nt) acc[il][nt] = (f32x4){0.f, 0.f, 0.f, 0.f};

  // prime chunk-0 operands (VMEM + LDS)
  uint4 htc = *(const uint4*)htrow;
  bf16x8 bc[5];
#pragma unroll
  for (int nt = 0; nt < 5; ++nt) bc[nt] = *(const bf16x8*)(wbp + (size_t)nt * 16 * D3);
  float4 hc[2][2];
#pragma unroll
  for (int il = 0; il < 2; ++il) {
    hc[il][0] = *(const float4*)&Hrow[il * D3 + q * 8];
    hc[il][1] = *(const float4*)&Hrow[il * D3 + q * 8 + 4];
  }

  for (int k0 = 0; k0 < D3; k0 += 32) {
    const int kn = (k0 + 32 < D3) ? k0 + 32 : 0;  // last iter: harmless reload
    // prefetch next chunk: global...
    const uint4 htn = *(const uint4*)(htrow + kn);
    bf16x8 bn[5];
#pragma unroll
    for (int nt = 0; nt < 5; ++nt) bn[nt] = *(const bf16x8*)(wbp + (size_t)nt * 16 * D3 + kn);
    // ...and LDS hr (broadcast ds_read_b128)
    float4 hn[2][2];
#pragma unroll
    for (int il = 0; il < 2; ++il) {
      hn[il][0] = *(const float4*)&Hrow[il * D3 + kn + q * 8];
      hn[il][1] = *(const float4*)&Hrow[il * D3 + kn + q * 8 + 4];
    }

    // unpack Ht once, shared across both i's
    const float t0 = lo16f(htc.x), t1 = hi16f(htc.x);
    const float t2 = lo16f(htc.y), t3 = hi16f(htc.y);
    const float t4 = lo16f(htc.z), t5 = hi16f(htc.z);
    const float t6 = lo16f(htc.w), t7 = hi16f(htc.w);

#pragma unroll
    for (int il = 0; il < 2; ++il) {
      union { bf16x8 v; uint32_t u[4]; } pk;
      pk.u[0] = pkrhu(fmaxf(t0 + hc[il][0].x, 0.f), fmaxf(t1 + hc[il][0].y, 0.f));
      pk.u[1] = pkrhu(fmaxf(t2 + hc[il][0].z, 0.f), fmaxf(t3 + hc[il][0].w, 0.f));
      pk.u[2] = pkrhu(fmaxf(t4 + hc[il][1].x, 0.f), fmaxf(t5 + hc[il][1].y, 0.f));
      pk.u[3] = pkrhu(fmaxf(t6 + hc[il][1].z, 0.f), fmaxf(t7 + hc[il][1].w, 0.f));
#pragma unroll
      for (int nt = 0; nt < 5; ++nt)
        acc[il][nt] = __builtin_amdgcn_mfma_f32_16x16x32_bf16(pk.v, bc[nt], acc[il][nt], 0, 0, 0);
    }

    htc = htn;
#pragma unroll
    for (int il = 0; il < 2; ++il) {
      hc[il][0] = hn[il][0];
      hc[il][1] = hn[il][1];
    }
#pragma unroll
    for (int nt = 0; nt < 5; ++nt) bc[nt] = bn[nt];
  }

  // epilogue: C layout col=lm (c), row=q*4+r (j within tile)
#pragma unroll
  for (int nt = 0; nt < 5; ++nt) {
    const int c = nt * 16 + lm;
    if (c < NC) {
      const float rb = relb[c];
      const int r = c / 3, tg = c % 3;
#pragma unroll
      for (int il = 0; il < 2; ++il) {
        float* base = out + ((((size_t)b * TAG + tg) * RR + r) * SS + (i0 + il)) * SS + w * 16 + q * 4;
        float4 o;
        o.x = acc[il][nt][0] + rb;
        o.y = acc[il][nt][1] + rb;
        o.z = acc[il][nt][2] + rb;
        o.w = acc[il][nt][3] + rb;
        *(float4*)base = o;
      }
    }
  }
}

// ---------------------------------------------------------------------------
extern "C" void kernel_launch(void* const* d_in, const int* in_sizes, int n_in,
                              void* d_out, int out_size, void* d_ws, size_t ws_size,
                              hipStream_t stream) {
  const float* enc   = (const float*)d_in[0];  // [8,96,768]
  const float* rel   = (const float*)d_in[1];  // [24,8,768]
  const float* projW = (const float*)d_in[2];  // [1536,2304]
  const float* projb = (const float*)d_in[3];  // [2304]
  const float* relW  = (const float*)d_in[4];  // [2304,72]
  const float* relb  = (const float*)d_in[5];  // [72]
  float* out = (float*)d_out;                  // [8,3,24,96,96]

  float* Hh = (float*)d_ws;                               // 768*2304 f32
  uint16_t* Htb = (uint16_t*)(Hh + (size_t)DD * D3);      // 768*2304 bf16
  uint16_t* Wb = Htb + (size_t)DD * D3;                   // 96*2304 bf16
  uint16_t* Tp = Wb + (size_t)96 * D3;                    // 2304*1536 bf16
  uint16_t* Ab = Tp + (size_t)D3 * 2 * DD;                // 768*768 bf16
  float* Pst = (float*)(Ab + (size_t)DD * DD);            // 8*8*96 f32

  k_prepW<<<(96 * D3) / 256, 256, 0, stream>>>(relW, Wb);
  k_trans<<<dim3(36, 24), 256, 0, stream>>>(projW, Tp);
  k_refA<<<BB, 256, 0, stream>>>(enc, rel, Pst);
  k_refB<<<48, 256, 0, stream>>>(enc, rel, Pst, Ab);
  k_proj<<<dim3(12, 72), 256, 0, stream>>>(Ab, Tp, projb, Hh, Htb);
  k_pairs<<<BB * 48, 384, 0, stream>>>(Hh, Htb, Wb, relb, out);
}

// Round 9
// 249.220 us; speedup vs baseline: 1.5561x; 1.2752x over previous
//
#include <hip/hip_runtime.h>
#include <hip/hip_bf16.h>
#include <math.h>
#include <stdint.h>
#include <string.h>

#define BB 8
#define SS 96
#define DD 768
#define RR 24
#define RSEQ 8
#define TAG 3
#define D3 2304   // 3*D
#define NC 72     // R*TAG

typedef __attribute__((ext_vector_type(8))) short bf16x8;
typedef __attribute__((ext_vector_type(4))) float f32x4;

// async global->LDS copy, 16 B/lane. LDS dest = wave-uniform base + lane*16;
// global src is per-lane. No destination VGPR => compiler cannot serialize it.
typedef __attribute__((address_space(3))) uint8_t lds_u8;
typedef const __attribute__((address_space(1))) uint8_t glb_u8;
static __device__ __forceinline__ void glld16(const void* g, void* l) {
  __builtin_amdgcn_global_load_lds((glb_u8*)g, (lds_u8*)l, 16, 0, 0);
}

// round-half-up f32 pair -> packed bf16x2: add,add,v_perm = 3 VALU.
static __device__ inline uint32_t pkrhu(float lo, float hi) {
  uint32_t a, b;
  memcpy(&a, &lo, 4);
  memcpy(&b, &hi, 4);
  return __builtin_amdgcn_perm(b + 0x8000u, a + 0x8000u, 0x07060302u);
}
static __device__ inline uint16_t bf16c(float v) {
  uint32_t u;
  memcpy(&u, &v, 4);
  u += 0x7FFFu + ((u >> 16) & 1u);
  return (uint16_t)(u >> 16);
}
static __device__ inline uint32_t pkrne(float lo, float hi) {
  uint32_t a, b;
  memcpy(&a, &lo, 4);
  memcpy(&b, &hi, 4);
  a += 0x7FFFu + ((a >> 16) & 1u);
  b += 0x7FFFu + ((b >> 16) & 1u);
  return (a >> 16) | (b & 0xFFFF0000u);
}
static __device__ inline float lo16f(uint32_t u) {
  const uint32_t v = u << 16;
  float f;
  memcpy(&f, &v, 4);
  return f;
}
static __device__ inline float hi16f(uint32_t u) {
  const uint32_t v = u & 0xFFFF0000u;
  float f;
  memcpy(&f, &v, 4);
  return f;
}

// ---------------------------------------------------------------------------
// Kernel P0 v2: Wb[96][2304] bf16 = rel_W^T, coalesced via LDS transpose.
// grid 36 (k-slices of 64), block 256. Reads 64 rows of relW = contiguous
// 4608 f32. Rows 72..79 written zero (n-tile padding); rows 80..95 untouched
// (read-only scratch for k_pairs' staging pad lanes).
// ---------------------------------------------------------------------------
__global__ __launch_bounds__(256) void k_prepW(const float* __restrict__ relW,
                                               uint16_t* __restrict__ Wb) {
  __shared__ float tile[64 * NC];  // [k][n] packed, 18.4 KB
  const int k0 = blockIdx.x * 64;
  const int t = threadIdx.x;
  const float* src = relW + (size_t)k0 * NC;  // contiguous 64*72 floats
  for (int e = t; e < 64 * NC / 4; e += 256) ((float4*)tile)[e] = ((const float4*)src)[e];
  __syncthreads();
  // 80 n-rows x 16 k-quads
  for (int u = t; u < 80 * 16; u += 256) {
    const int n = u >> 4, kq = (u & 15) * 4;
    uint2 w = {0u, 0u};
    if (n < NC) {
      w.x = pkrne(tile[(kq + 0) * NC + n], tile[(kq + 1) * NC + n]);
      w.y = pkrne(tile[(kq + 2) * NC + n], tile[(kq + 3) * NC + n]);
    }
    *(uint2*)&Wb[(size_t)n * D3 + k0 + kq] = w;
  }
}

// ---------------------------------------------------------------------------
// Kernel P1: T[2304][1536] bf16 = proj_W^T, 64x64 LDS-tiled transpose.
// ---------------------------------------------------------------------------
__global__ __launch_bounds__(256) void k_trans(const float* __restrict__ W,
                                               uint16_t* __restrict__ T) {
  __shared__ float tile[64][65];
  const int c0 = blockIdx.x * 64;
  const int r0 = blockIdx.y * 64;
  const int t = threadIdx.x;
  {
    const int tr = t >> 4;
    const int tc4 = (t & 15) * 4;
#pragma unroll
    for (int p = 0; p < 4; ++p) {
      const int r = tr + p * 16;
      const float4 v = *(const float4*)&W[(size_t)(r0 + r) * D3 + c0 + tc4];
      tile[r][tc4 + 0] = v.x;
      tile[r][tc4 + 1] = v.y;
      tile[r][tc4 + 2] = v.z;
      tile[r][tc4 + 3] = v.w;
    }
  }
  __syncthreads();
  {
    const int cc = t >> 4;
    const int rr4 = (t & 15) * 4;
#pragma unroll
    for (int p = 0; p < 4; ++p) {
      const int c = cc + p * 16;
      uint2 w;
      w.x = pkrne(tile[rr4 + 0][c], tile[rr4 + 1][c]);
      w.y = pkrne(tile[rr4 + 2][c], tile[rr4 + 3][c]);
      *(uint2*)&T[(size_t)(c0 + c) * (2 * DD) + r0 + rr4] = w;
    }
  }
}

// ---------------------------------------------------------------------------
// Kernel 1a: refine, serial part. G+S0 fused 8x104 product, then 24
// collapsed attention steps. Writes P[8][96]. grid 8.
// ---------------------------------------------------------------------------
__global__ __launch_bounds__(256) void k_refA(const float* __restrict__ enc,
                                              const float* __restrict__ rel,
                                              float* __restrict__ Pst) {
  const int b = blockIdx.x;
  const int t = threadIdx.x;
  __shared__ float As[RSEQ][DD + 4];
  __shared__ float S0[RSEQ][SS];
  __shared__ float G[RSEQ][RSEQ];
  __shared__ float P[RSEQ][SS];
  __shared__ float sc[RSEQ][SS];
  const float scale = 0.036084391824351613f;  // 1/sqrt(768)

  const float* Ag = rel + (size_t)b * RSEQ * DD;
  for (int e = t; e < RSEQ * DD; e += 256) As[e / DD][e % DD] = Ag[e];
  for (int e = t; e < RSEQ * SS; e += 256) ((float*)P)[e] = 0.f;
  __syncthreads();

  const float* Eb = enc + (size_t)b * SS * DD;
  for (int e = t; e < RSEQ * (SS + RSEQ); e += 256) {
    const int r = e & 7, s = e >> 3;
    const float* row = (s < SS) ? (Eb + (size_t)s * DD) : &As[s - SS][0];
    float a0 = 0.f, a1 = 0.f, a2 = 0.f, a3 = 0.f;
    for (int d = 0; d < DD; d += 4) {
      const float4 rv = *(const float4*)&row[d];
      a0 += As[r][d + 0] * rv.x;
      a1 += As[r][d + 1] * rv.y;
      a2 += As[r][d + 2] * rv.z;
      a3 += As[r][d + 3] * rv.w;
    }
    const float acc = a0 + a1 + a2 + a3;
    if (s < SS) S0[r][s] = acc;
    else G[r][s - SS] = acc;
  }
  __syncthreads();

  const int wave = t >> 6, lane = t & 63;
  for (int step = 0; step < RR; ++step) {
    for (int e = t; e < RSEQ * SS; e += 256) {
      const int r = e / SS, s = e % SS;
      float acc = S0[r][s];
#pragma unroll
      for (int r2 = 0; r2 < RSEQ; ++r2) acc += G[r][r2] * P[r2][s];
      sc[r][s] = acc * scale;
    }
    __syncthreads();
#pragma unroll
    for (int rr = 0; rr < 2; ++rr) {
      const int r = wave * 2 + rr;
      const float m1 = sc[r][lane];
      const float m2 = (lane < 32) ? sc[r][lane + 64] : -1e30f;
      float mx = fmaxf(m1, m2);
#pragma unroll
      for (int o = 32; o > 0; o >>= 1) mx = fmaxf(mx, __shfl_xor(mx, o, 64));
      const float e1 = __expf(m1 - mx);
      const float e2 = (lane < 32) ? __expf(m2 - mx) : 0.f;
      float sm = e1 + e2;
#pragma unroll
      for (int o = 32; o > 0; o >>= 1) sm += __shfl_xor(sm, o, 64);
      const float inv = 1.f / sm;
      P[r][lane] += e1 * inv;
      if (lane < 32) P[r][lane + 64] += e2 * inv;
    }
    __syncthreads();
  }

  for (int e = t; e < RSEQ * SS; e += 256) Pst[(size_t)b * RSEQ * SS + e] = ((float*)P)[e];
}

// ---------------------------------------------------------------------------
// Kernel 1b: refine epilogue (parallel): enc' bf16 = enc + P^T @ A. grid 48.
// ---------------------------------------------------------------------------
__global__ __launch_bounds__(256) void k_refB(const float* __restrict__ enc,
                                              const float* __restrict__ rel,
                                              const float* __restrict__ Pst,
                                              uint16_t* __restrict__ encRb) {
  const int blk = blockIdx.x;
  const int b = blk / 6;
  const int s0 = (blk % 6) * 16;
  const int t = threadIdx.x;
  __shared__ float As[RSEQ][DD + 4];
  __shared__ float Pl[RSEQ][16];

  const float* Ag = rel + (size_t)b * RSEQ * DD;
  for (int e = t; e < RSEQ * DD / 4; e += 256) {
    const int r = (e * 4) / DD, d = (e * 4) % DD;
    *(float4*)&As[r][d] = *(const float4*)&Ag[e * 4];
  }
  if (t < RSEQ * 16) {
    const int r = t >> 4, sl = t & 15;
    Pl[r][sl] = Pst[(size_t)b * RSEQ * SS + r * SS + s0 + sl];
  }
  __syncthreads();

  const float* Eb = enc + ((size_t)b * SS + s0) * DD;
  uint16_t* Ob = encRb + ((size_t)b * SS + s0) * DD;
  for (int e = t; e < 16 * DD / 4; e += 256) {
    const int sl = (e * 4) / DD, d = (e * 4) % DD;
    float4 v = ((const float4*)Eb)[e];
#pragma unroll
    for (int r = 0; r < RSEQ; ++r) {
      const float p = Pl[r][sl];
      v.x += p * As[r][d + 0];
      v.y += p * As[r][d + 1];
      v.z += p * As[r][d + 2];
      v.w += p * As[r][d + 3];
    }
    uint2 w;
    w.x = pkrhu(v.x, v.y);
    w.y = pkrhu(v.z, v.w);
    *(uint2*)&Ob[e * 4] = w;
  }
}

// ---------------------------------------------------------------------------
// Kernel 2: projection GEMM, bf16 MFMA, LDS-staged (unchanged).
// ---------------------------------------------------------------------------
__global__ __launch_bounds__(256, 4) void k_proj(const uint16_t* __restrict__ Ab,
                                                 const uint16_t* __restrict__ Bt,
                                                 const float* __restrict__ pb,
                                                 float* __restrict__ Hh,
                                                 uint16_t* __restrict__ Htb) {
  const int m0 = blockIdx.x * 64;
  const int gn0 = blockIdx.y * 64;
  const bool isH = gn0 < D3;               // uniform per block
  const int n0 = isH ? gn0 : gn0 - D3;
  const int halfk = isH ? 0 : DD;
  const int t = threadIdx.x, w = t >> 6, lane = t & 63;
  const int wm = w >> 1, wn = w & 1;
  const int lm = lane & 15, q = lane >> 4;

  __shared__ uint16_t As[64][80];
  __shared__ uint16_t Bs[64][80];

  const int srow = t >> 3;
  const int sq8 = (t & 7) * 8;

  f32x4 acc[2][2];
#pragma unroll
  for (int a = 0; a < 2; ++a)
#pragma unroll
    for (int c = 0; c < 2; ++c) acc[a][c] = (f32x4){0.f, 0.f, 0.f, 0.f};

  const uint16_t* aSrc = Ab + (size_t)(m0 + srow) * DD + sq8;
  const uint16_t* bSrc = Bt + (size_t)(n0 + srow) * (2 * DD) + halfk + sq8;

  for (int k0 = 0; k0 < DD; k0 += 64) {
    const uint4 a0 = *(const uint4*)(aSrc + k0);
    const uint4 a1 = *(const uint4*)(aSrc + 32 * DD + k0);
    const uint4 b0 = *(const uint4*)(bSrc + k0);
    const uint4 b1 = *(const uint4*)(bSrc + 32 * (2 * DD) + k0);
    __syncthreads();
    *(uint4*)&As[srow][sq8] = a0;
    *(uint4*)&As[srow + 32][sq8] = a1;
    *(uint4*)&Bs[srow][sq8] = b0;
    *(uint4*)&Bs[srow + 32][sq8] = b1;
    __syncthreads();
#pragma unroll
    for (int kk = 0; kk < 2; ++kk) {
      bf16x8 af[2], bf[2];
#pragma unroll
      for (int mt = 0; mt < 2; ++mt)
        af[mt] = *(const bf16x8*)&As[wm * 32 + mt * 16 + lm][kk * 32 + q * 8];
#pragma unroll
      for (int nt = 0; nt < 2; ++nt)
        bf[nt] = *(const bf16x8*)&Bs[wn * 32 + nt * 16 + lm][kk * 32 + q * 8];
#pragma unroll
      for (int nt = 0; nt < 2; ++nt)
#pragma unroll
        for (int mt = 0; mt < 2; ++mt)
          acc[mt][nt] = __builtin_amdgcn_mfma_f32_16x16x32_bf16(af[mt], bf[nt], acc[mt][nt], 0, 0, 0);
    }
  }

#pragma unroll
  for (int nt = 0; nt < 2; ++nt) {
    const int ncol = n0 + wn * 32 + nt * 16 + lm;
    const int mrow = m0 + wm * 32 + q * 4;
    if (isH) {
      const float bias = pb[ncol];
#pragma unroll
      for (int mt = 0; mt < 2; ++mt)
#pragma unroll
        for (int r = 0; r < 4; ++r)
          Hh[(size_t)(mrow + mt * 16 + r) * D3 + ncol] = acc[mt][nt][r] + bias;
    } else {
#pragma unroll
      for (int mt = 0; mt < 2; ++mt)
#pragma unroll
        for (int r = 0; r < 4; ++r)
          Htb[(size_t)(mrow + mt * 16 + r) * D3 + ncol] = bf16c(acc[mt][nt][r]);
    }
  }
}

// ---------------------------------------------------------------------------
// Kernel 3: pairwise GEMM v6 -- m97-style async staging.
// Block=(b,i), grid 768 (3/CU), 384 thr / 6 waves: wave=(wm in {0,1,2} j-half
// of 32, wn in {0,1}: n-tiles {0,1,2} or {3,4}). Per BK=64 chunk:
//   barrier; issue ~4 global_load_lds dwordx4/wave (Ht 96x64 + Wb 80x64 bf16
//   into 144-B-stride padded LDS rows); barrier (drains vmcnt);
//   compute = pure LDS reads + A-build VALU + MFMA. No VMEM->VGPR loads in
//   the loop => nothing for the compiler to serialize.
// 144-B row stride: b128 reads spread over all 8 bank-groups (floor tput).
// ---------------------------------------------------------------------------
#define HTS_BYTES (96 * 144)                  // 13824
#define STG_BYTES (HTS_BYTES + 80 * 144)      // 25344
#define STG_ISSUES ((STG_BYTES + 1023) / 1024)  // 25
#define WOFF (HTS_BYTES / 2)                  // 6912 elems

__global__ __launch_bounds__(384, 5) void k_pairs(const float* __restrict__ Hh,
                                                  const uint16_t* __restrict__ Htb,
                                                  const uint16_t* __restrict__ Wb,
                                                  const float* __restrict__ relb,
                                                  float* __restrict__ out) {
  const int bi = blockIdx.x;
  const int b = bi / SS, i = bi % SS;
  const int t = threadIdx.x;
  const int w = t >> 6, lane = t & 63;
  const int lm = lane & 15, q = lane >> 4;
  const int wm = w >> 1, wn = w & 1;
  const int ntn = wn ? 2 : 3;  // n-tiles this wave

  __shared__ __align__(16) float Hrow[D3];          // 9216 B (= 9 issues)
  __shared__ __align__(16) uint16_t Stg[12800];     // 25600 B (25 issues incl. tail pad)

  // ---- one-time: stage Hrow (f32 row i of Hh) via async copy ----
  {
    const char* hh = (const char*)(Hh + (size_t)bi * D3);
#pragma unroll
    for (int r = 0; r < 2; ++r) {
      const int idx = w + 6 * r;
      if (idx < 9) glld16(hh + idx * 1024 + lane * 16, (char*)Hrow + idx * 1024);
    }
  }

  // ---- per-lane source pointers for the chunk staging (k0-invariant) ----
  const char* rp[5];
#pragma unroll
  for (int r = 0; r < 5; ++r) {
    const int idx = w + 6 * r;
    if (idx < STG_ISSUES) {
      const int beta = idx * 1024 + lane * 16;
      int elem, row, o;
      const char* base;
      if (beta < HTS_BYTES) {
        elem = beta >> 1;
        row = elem / 72;
        o = elem - row * 72;
        base = (const char*)(Htb + ((size_t)b * SS + row) * D3);
      } else {
        elem = (beta - HTS_BYTES) >> 1;
        row = elem / 72;
        o = elem - row * 72;
        base = (const char*)(Wb + (size_t)row * D3);  // rows >=80 exist (scratch)
      }
      if (o >= 64) o = 0;  // pad lanes: read valid addr, land in unused LDS pad
      rp[r] = base + 2 * o;
    } else {
      rp[r] = nullptr;
    }
  }

  f32x4 acc[2][3];
#pragma unroll
  for (int mt = 0; mt < 2; ++mt)
#pragma unroll
    for (int nt = 0; nt < 3; ++nt) acc[mt][nt] = (f32x4){0.f, 0.f, 0.f, 0.f};

  for (int k0 = 0; k0 < D3; k0 += 64) {
    __syncthreads();  // all waves done reading Stg (prev chunk); also orders iter-0
    // issue async staging for this chunk (no destination registers!)
#pragma unroll
    for (int r = 0; r < 5; ++r) {
      const int idx = w + 6 * r;
      if (idx < STG_ISSUES) glld16(rp[r] + 2 * k0, (char*)Stg + idx * 1024);
    }
    __syncthreads();  // compiler emits vmcnt(0) drain: staged data visible

#pragma unroll
    for (int kk = 0; kk < 2; ++kk) {
      const int ko = kk * 32 + q * 8;
      const float4 h0 = *(const float4*)&Hrow[k0 + ko];      // broadcast
      const float4 h1 = *(const float4*)&Hrow[k0 + ko + 4];  // broadcast
      bf16x8 af[2];
#pragma unroll
      for (int mt = 0; mt < 2; ++mt) {
        const int j = wm * 32 + mt * 16 + lm;
        union { bf16x8 v; uint32_t u[4]; } hu, pk;
        hu.v = *(const bf16x8*)&Stg[j * 72 + ko];
        pk.u[0] = pkrhu(fmaxf(lo16f(hu.u[0]) + h0.x, 0.f), fmaxf(hi16f(hu.u[0]) + h0.y, 0.f));
        pk.u[1] = pkrhu(fmaxf(lo16f(hu.u[1]) + h0.z, 0.f), fmaxf(hi16f(hu.u[1]) + h0.w, 0.f));
        pk.u[2] = pkrhu(fmaxf(lo16f(hu.u[2]) + h1.x, 0.f), fmaxf(hi16f(hu.u[2]) + h1.y, 0.f));
        pk.u[3] = pkrhu(fmaxf(lo16f(hu.u[3]) + h1.z, 0.f), fmaxf(hi16f(hu.u[3]) + h1.w, 0.f));
        af[mt] = pk.v;
      }
#pragma unroll
      for (int nt = 0; nt < 3; ++nt) {
        if (nt < ntn) {
          const int n = (wn * 3 + nt) * 16 + lm;
          const bf16x8 bf = *(const bf16x8*)&Stg[WOFF + n * 72 + ko];
          acc[0][nt] = __builtin_amdgcn_mfma_f32_16x16x32_bf16(af[0], bf, acc[0][nt], 0, 0, 0);
          acc[1][nt] = __builtin_amdgcn_mfma_f32_16x16x32_bf16(af[1], bf, acc[1][nt], 0, 0, 0);
        }
      }
    }
  }

  // epilogue: C layout col=lm (c), row=q*4+r (j within 16-tile)
#pragma unroll
  for (int nt = 0; nt < 3; ++nt) {
    if (nt < ntn) {
      const int c = (wn * 3 + nt) * 16 + lm;
      if (c < NC) {
        const float rb = relb[c];
        const int rr = c / 3, tg = c % 3;
#pragma unroll
        for (int mt = 0; mt < 2; ++mt) {
          const int j0 = wm * 32 + mt * 16 + q * 4;
          float* base = out + ((((size_t)b * TAG + tg) * RR + rr) * SS + i) * SS + j0;
          float4 o;
          o.x = acc[mt][nt][0] + rb;
          o.y = acc[mt][nt][1] + rb;
          o.z = acc[mt][nt][2] + rb;
          o.w = acc[mt][nt][3] + rb;
          *(float4*)base = o;
        }
      }
    }
  }
}

// ---------------------------------------------------------------------------
extern "C" void kernel_launch(void* const* d_in, const int* in_sizes, int n_in,
                              void* d_out, int out_size, void* d_ws, size_t ws_size,
                              hipStream_t stream) {
  const float* enc   = (const float*)d_in[0];  // [8,96,768]
  const float* rel   = (const float*)d_in[1];  // [24,8,768]
  const float* projW = (const float*)d_in[2];  // [1536,2304]
  const float* projb = (const float*)d_in[3];  // [2304]
  const float* relW  = (const float*)d_in[4];  // [2304,72]
  const float* relb  = (const float*)d_in[5];  // [72]
  float* out = (float*)d_out;                  // [8,3,24,96,96]

  float* Hh = (float*)d_ws;                               // 768*2304 f32
  uint16_t* Htb = (uint16_t*)(Hh + (size_t)DD * D3);      // 768*2304 bf16
  uint16_t* Wb = Htb + (size_t)DD * D3;                   // 96*2304 bf16 (80 used)
  uint16_t* Tp = Wb + (size_t)96 * D3;                    // 2304*1536 bf16
  uint16_t* Ab = Tp + (size_t)D3 * 2 * DD;                // 768*768 bf16
  float* Pst = (float*)(Ab + (size_t)DD * DD);            // 8*8*96 f32

  k_prepW<<<36, 256, 0, stream>>>(relW, Wb);
  k_trans<<<dim3(36, 24), 256, 0, stream>>>(projW, Tp);
  k_refA<<<BB, 256, 0, stream>>>(enc, rel, Pst);
  k_refB<<<48, 256, 0, stream>>>(enc, rel, Pst, Ab);
  k_proj<<<dim3(12, 72), 256, 0, stream>>>(Ab, Tp, projb, Hh, Htb);
  k_pairs<<<BB * SS, 384, 0, stream>>>(Hh, Htb, Wb, relb, out);
}